// Round 5
// baseline (110.445 us; speedup 1.0000x reference)
//
#include <hip/hip_runtime.h>
#include <stdint.h>

#define NQ 8

// v_sin/v_cos take input in REVOLUTIONS. Fold the /2 (half-angle) and 1/2pi
// into one multiplier applied to the raw angle.
#define HALF_INV2PI 0.07957747154594767f   // 0.5 * 1/(2*pi)

// ---- packed 2xf32 (full-rate on CDNA2+): amplitude = (re, im) in a VGPR pair ----
typedef float f32x2 __attribute__((ext_vector_type(2)));

__device__ __forceinline__ f32x2 pk2(float x, float y) { f32x2 r; r.x = x; r.y = y; return r; }
__device__ __forceinline__ f32x2 pkb(float x)          { f32x2 r; r.x = x; r.y = x; return r; }

// d = a*b + c on both halves, one VALU instruction each (VOP3P).
__device__ __forceinline__ f32x2 pk_fma(f32x2 a, f32x2 b, f32x2 c) {
    f32x2 d;
    asm("v_pk_fma_f32 %0, %1, %2, %3" : "=v"(d) : "v"(a), "v"(b), "v"(c));
    return d;
}
__device__ __forceinline__ f32x2 pk_mul(f32x2 a, f32x2 b) {
    f32x2 d;
    asm("v_pk_mul_f32 %0, %1, %2" : "=v"(d) : "v"(a), "v"(b));
    return d;
}
// Cross-component variants via VOP3P op_sel/neg modifiers (packed-f32 op_sel
// selects which 32-bit register of the 64-bit source feeds each result half):
// d.lo = a.hi*b.lo + c.lo ; d.hi = a.lo*(-b.hi) + c.hi    [swap a; negate b's hi term]
__device__ __forceinline__ f32x2 pk_fma_sa_nh(f32x2 a, f32x2 b, f32x2 c) {
    f32x2 d;
    asm("v_pk_fma_f32 %0, %1, %2, %3 op_sel:[1,0,0] op_sel_hi:[0,1,1] neg_hi:[0,1,0]"
        : "=v"(d) : "v"(a), "v"(b), "v"(c));
    return d;
}
// d.lo = a.hi*(-b.lo) + c.lo ; d.hi = a.lo*b.hi + c.hi    [swap a; negate b's lo term]
__device__ __forceinline__ f32x2 pk_fma_sa_nl(f32x2 a, f32x2 b, f32x2 c) {
    f32x2 d;
    asm("v_pk_fma_f32 %0, %1, %2, %3 op_sel:[1,0,0] op_sel_hi:[0,1,1] neg_lo:[0,1,0]"
        : "=v"(d) : "v"(a), "v"(b), "v"(c));
    return d;
}
// d.lo = a.lo*b.lo + c.lo ; d.hi = a.hi*(-b.hi) + c.hi    [no swap; negate b's hi term]
__device__ __forceinline__ f32x2 pk_fma_nh(f32x2 a, f32x2 b, f32x2 c) {
    f32x2 d;
    asm("v_pk_fma_f32 %0, %1, %2, %3 neg_hi:[0,1,0]"
        : "=v"(d) : "v"(a), "v"(b), "v"(c));
    return d;
}

// ---- cross-lane xor exchange within aligned 32-lane groups ----
// xor1/xor2: DPP quad_perm; xor8: DPP row_ror:8 (within 16-lane rows, ror8 == xor8).
// xor4/xor16: ds_swizzle BitMode (operates within 32-lane groups).
template<int XM>
__device__ __forceinline__ float sx(float v) {
    if constexpr (XM == 0) return v;
    const int x = __float_as_int(v);
    int r;
    if constexpr (XM == 1)      r = __builtin_amdgcn_update_dpp(0, x, 0xB1,  0xF, 0xF, true); // quad [1,0,3,2]
    else if constexpr (XM == 2) r = __builtin_amdgcn_update_dpp(0, x, 0x4E,  0xF, 0xF, true); // quad [2,3,0,1]
    else if constexpr (XM == 8) r = __builtin_amdgcn_update_dpp(0, x, 0x128, 0xF, 0xF, true); // row_ror:8
    else                        r = __builtin_amdgcn_ds_swizzle(x, (XM << 10) | 0x1F);        // 4, 16
    return __int_as_float(r);
}

// full (re,im) partner fetch: two 32-bit exchanges
template<int XM>
__device__ __forceinline__ f32x2 sxp(f32x2 v) {
    f32x2 r; r.x = sx<XM>(v.x); r.y = sx<XM>(v.y); return r;
}
// partner fetched with components SWAPPED: returns (partner.im, partner.re)
template<int XM>
__device__ __forceinline__ f32x2 sxp_swap(f32x2 v) {
    f32x2 r; r.x = sx<XM>(v.y); r.y = sx<XM>(v.x); return r;
}

__device__ __forceinline__ void swapv(f32x2& a, f32x2& b) { f32x2 t = a; a = b; b = t; }

// Layout: amp index g = i | (laneq<<3); qubit k -> bit k of g.
// Qubits 0..2 = local bits (i in [0,8)), qubits 3..7 = lane bits (laneq in [0,32)).

// ---- real 2x2 [[a,b],[d,e]] on qubit Q — packed: same real coef on re and im ----
template<int Q>
__device__ __forceinline__ void realGate(f32x2 (&v)[8], int laneq,
                                         float a, float b, float d, float e)
{
    if constexpr (Q < 3) {
        constexpr int M = 1 << Q;
        const f32x2 a2 = pkb(a), b2 = pkb(b), d2 = pkb(d), e2 = pkb(e);
#pragma unroll
        for (int i = 0; i < 8; i++) if (!(i & M)) {
            const int j = i | M;
            const f32x2 x0 = v[i], x1 = v[j];
            v[i] = pk_fma(a2, x0, pk_mul(b2, x1));
            v[j] = pk_fma(d2, x0, pk_mul(e2, x1));
        }
    } else {
        constexpr int XM = 1 << (Q - 3);
        const int bit = (laneq >> (Q - 3)) & 1;
        const f32x2 sc2 = pkb(bit ? e : a);   // self coefficient
        const f32x2 pc2 = pkb(bit ? d : b);   // partner coefficient
#pragma unroll
        for (int i = 0; i < 8; i++) {
            const f32x2 p = sxp<XM>(v[i]);
            v[i] = pk_fma(sc2, v[i], pk_mul(pc2, p));
        }
    }
}

// ---- RX: [[c, -i s], [-i s, c]] ----
// new.re = c*re + s*partner.im ; new.im = c*im - s*partner.re
template<int Q>
__device__ __forceinline__ void applyRX(f32x2 (&v)[8], int laneq, float c, float s)
{
    const f32x2 cc = pkb(c), ss = pkb(s);
    if constexpr (Q < 3) {
        constexpr int M = 1 << Q;
#pragma unroll
        for (int i = 0; i < 8; i++) if (!(i & M)) {
            const int j = i | M;
            const f32x2 x0 = v[i], x1 = v[j];
            // (c*x0r + s*x1i, c*x0i - s*x1r) via op_sel swap of the partner
            v[i] = pk_fma_sa_nh(x1, ss, pk_mul(cc, x0));
            v[j] = pk_fma_sa_nh(x0, ss, pk_mul(cc, x1));
        }
    } else {
        constexpr int XM = 1 << (Q - 3);
#pragma unroll
        for (int i = 0; i < 8; i++) {
            const f32x2 ps = sxp_swap<XM>(v[i]);   // (partner.im, partner.re)
            v[i] = pk_fma_nh(ps, ss, pk_mul(cc, v[i]));
        }
    }
}

// ---- RZ: diag(c - i s, c + i s) — shuffle-free, 2 pk ops per amp ----
template<int Q>
__device__ __forceinline__ void applyRZ(f32x2 (&v)[8], int laneq, float c, float s)
{
    const f32x2 cc = pkb(c);
    if constexpr (Q >= 3) {
        const int bit = (laneq >> (Q - 3)) & 1;
        const float t = bit ? -s : s;
        const f32x2 tt = pkb(t);
#pragma unroll
        for (int i = 0; i < 8; i++)
            v[i] = pk_fma_sa_nh(v[i], tt, pk_mul(cc, v[i]));   // (c*r + t*i, c*i - t*r)
    } else {
        const f32x2 ss = pkb(s);
#pragma unroll
        for (int i = 0; i < 8; i++) {
            if ((i >> Q) & 1) v[i] = pk_fma_sa_nl(v[i], ss, pk_mul(cc, v[i])); // t = -s
            else              v[i] = pk_fma_sa_nh(v[i], ss, pk_mul(cc, v[i])); // t = +s
        }
    }
}

// ---- Pauli Z ----
template<int Q>
__device__ __forceinline__ void applyZ(f32x2 (&v)[8], int laneq)
{
    if constexpr (Q >= 3) {
        const bool f = ((laneq >> (Q - 3)) & 1) != 0;
#pragma unroll
        for (int i = 0; i < 8; i++) {
            v[i].x = f ? -v[i].x : v[i].x;
            v[i].y = f ? -v[i].y : v[i].y;
        }
    } else {
#pragma unroll
        for (int i = 0; i < 8; i++) if ((i >> Q) & 1) {
            v[i].x = -v[i].x; v[i].y = -v[i].y;
        }
    }
}

// ---- Pauli X ----
template<int Q>
__device__ __forceinline__ void applyX(f32x2 (&v)[8], int laneq)
{
    if constexpr (Q < 3) {
        constexpr int M = 1 << Q;
#pragma unroll
        for (int i = 0; i < 8; i++) if (!(i & M)) {
            swapv(v[i], v[i | M]);
        }
    } else {
        constexpr int XM = 1 << (Q - 3);
#pragma unroll
        for (int i = 0; i < 8; i++) {
            v[i] = sxp<XM>(v[i]);
        }
    }
}

// ---- Pauli Y: [[0,-i],[i,0]] ----
template<int Q>
__device__ __forceinline__ void applyY(f32x2 (&v)[8], int laneq)
{
    if constexpr (Q < 3) {
        constexpr int M = 1 << Q;
#pragma unroll
        for (int i = 0; i < 8; i++) if (!(i & M)) {
            const int j = i | M;
            const f32x2 x0 = v[i], x1 = v[j];
            v[i] = pk2(x1.y, -x1.x);
            v[j] = pk2(-x0.y, x0.x);
        }
    } else {
        constexpr int XM = 1 << (Q - 3);
        const int bit = (laneq >> (Q - 3)) & 1;
#pragma unroll
        for (int i = 0; i < 8; i++) {
            const f32x2 p = sxp<XM>(v[i]);
            v[i].x = bit ? -p.y : p.y;
            v[i].y = bit ? p.x : -p.x;
        }
    }
}

// ---- CZ(C,T): sign flip when both bits set — shuffle-free ----
template<int C, int T>
__device__ __forceinline__ void applyCZ(f32x2 (&v)[8], int laneq)
{
#pragma unroll
    for (int i = 0; i < 8; i++) {
        const int g = i | (laneq << 3);
        const bool f = (((g >> C) & (g >> T)) & 1) != 0;
        v[i].x = f ? -v[i].x : v[i].x;
        v[i].y = f ? -v[i].y : v[i].y;
    }
}

// ---- controlled bit-flip: new[g] = old[g ^ M] when (g & CM) == CM ----
template<int CM, int M>
__device__ __forceinline__ void applyCPerm(f32x2 (&v)[8], int laneq)
{
    constexpr int LX  = M >> 3;    // target in lane bits -> exchange mask
    constexpr int PL  = M & 7;     // target in local bits
    constexpr int CML = CM & 7;    // controls in local bits
    constexpr int CMH = CM >> 3;   // controls in lane bits
    if constexpr (LX != 0) {
#pragma unroll
        for (int i = 0; i < 8; i++) {
            if ((i & CML) == CML) {
                const f32x2 p = sxp<LX>(v[i]);
                if constexpr (CMH != 0) {
                    const bool c = (laneq & CMH) == CMH;
                    v[i].x = c ? p.x : v[i].x;
                    v[i].y = c ? p.y : v[i].y;
                } else {
                    v[i] = p;
                }
            }
        }
    } else {
#pragma unroll
        for (int i = 0; i < 8; i++) {
            if (!(i & PL) && ((i & CML) == CML)) {
                const int j = i | PL;
                if constexpr (CMH != 0) {
                    const bool c = (laneq & CMH) == CMH;
                    const f32x2 t0 = v[i];
                    v[i].x = c ? v[j].x : v[i].x;  v[i].y = c ? v[j].y : v[i].y;
                    v[j].x = c ? t0.x : v[j].x;    v[j].y = c ? t0.y : v[j].y;
                } else {
                    swapv(v[i], v[j]);
                }
            }
        }
    }
}

// ---- CSWAP(C; T1,T2): swap bits T1,T2 when control set ----
template<int C, int T1, int T2>
__device__ __forceinline__ void applyCSWAP(f32x2 (&v)[8], int laneq)
{
    constexpr int M  = (1 << T1) | (1 << T2);
    constexpr int LX = M >> 3;
    constexpr int PL = M & 7;

    if constexpr (LX == 0) {
        // both targets local: representative i has T1-bit=1, T2-bit=0
#pragma unroll
        for (int i = 0; i < 8; i++) {
            if (((i >> T1) & 1) && !((i >> T2) & 1)) {
                bool skip = false;
                if constexpr (C < 3) { if (!((i >> C) & 1)) skip = true; }
                if (!skip) {
                    const int j = i ^ PL;
                    if constexpr (C >= 3) {
                        const bool c = ((laneq >> (C - 3)) & 1) != 0;
                        const f32x2 t0 = v[i];
                        v[i].x = c ? v[j].x : v[i].x;  v[i].y = c ? v[j].y : v[i].y;
                        v[j].x = c ? t0.x : v[j].x;    v[j].y = c ? t0.y : v[j].y;
                    } else {
                        swapv(v[i], v[j]);
                    }
                }
            }
        }
    } else if constexpr (PL == 0) {
        // both targets in lane bits
        bool c = ((((laneq >> (T1 - 3)) ^ (laneq >> (T2 - 3))) & 1) != 0);
        if constexpr (C >= 3) c = c && (((laneq >> (C - 3)) & 1) != 0);
#pragma unroll
        for (int i = 0; i < 8; i++) {
            bool skip = false;
            if constexpr (C < 3) { if (!((i >> C) & 1)) skip = true; }
            if (!skip) {
                const f32x2 p = sxp<LX>(v[i]);
                v[i].x = c ? p.x : v[i].x;
                v[i].y = c ? p.y : v[i].y;
            }
        }
    } else {
        // mixed: one local target (PL), one lane target (LX)
        constexpr int TL = (PL == (1 << T1)) ? T2 : T1;    // lane-resident target
        const bool laneT = ((laneq >> (TL - 3)) & 1) != 0;
        bool cc = true;
        if constexpr (C >= 3) cc = ((laneq >> (C - 3)) & 1) != 0;
#pragma unroll
        for (int i = 0; i < 8; i++) {
            if (!(i & PL)) {
                bool skip = false;
                if constexpr (C < 3) { if (!((i >> C) & 1)) skip = true; }
                if (!skip) {
                    const int j = i | PL;
                    // read partner-lane values before any write (lockstep)
                    const f32x2 a = sxp<LX>(v[j]);  // -> v[i]
                    const f32x2 b = sxp<LX>(v[i]);  // -> v[j]
                    const bool ci = cc && laneT;
                    const bool cj = cc && !laneT;
                    v[i].x = ci ? a.x : v[i].x;  v[i].y = ci ? a.y : v[i].y;
                    v[j].x = cj ? b.x : v[j].x;  v[j].y = cj ? b.y : v[j].y;
                }
            }
        }
    }
}

// ---- one node step; node N compile-time; design bits passed as packed scalars ----
// dryL: 4 bits (node&3), drotL: 8 bits (2 per node&3), dg2L: 16 bits (4 per node&3)
// All sincos values come from LDS (computed once in the prologue):
//   ryCS[n]  = (cos(feat_n/2), sin(feat_n/2))   per batch element (broadcast in group)
//   rotCS[k] = (cos(qp_k/2),  sin(qp_k/2))      block-uniform broadcast
template<int N>
__device__ __forceinline__ void nodeStep(f32x2 (&v)[8], int laneq,
                                         const float2* ryCS, const float2* rotCS,
                                         int layer, int dryL, int drotL, int dg2L)
{
    constexpr int N1 = (N + 1) & 7;
    constexpr int N2 = (N + 2) & 7;
    constexpr int SL = N & 3;

    const bool ryOn = ((dryL >> SL) & 1) != 0;
    const int rot = (drotL >> (2 * SL)) & 3;

    if (rot < 3) {
        const float2 t = rotCS[layer * NQ + N];     // ds_read_b64, uniform addr
        const float cb = t.x, sb = t.y;
        if (ryOn && rot == 1) {
            // RY(a) then RY(b) == RY(a+b): angle-sum on the cached pairs
            const float2 a = ryCS[N];
            const float c = cb * a.x - sb * a.y;
            const float s = sb * a.x + cb * a.y;
            realGate<N>(v, laneq, c, -s, s, c);
        } else {
            if (ryOn) {
                const float2 a = ryCS[N];
                realGate<N>(v, laneq, a.x, -a.y, a.y, a.x);
            }
            if (rot == 0)      applyRX<N>(v, laneq, cb, sb);
            else if (rot == 1) realGate<N>(v, laneq, cb, -sb, sb, cb);
            else               applyRZ<N>(v, laneq, cb, sb);
        }
    } else if (ryOn) {
        const float2 a = ryCS[N];
        realGate<N>(v, laneq, a.x, -a.y, a.y, a.x);
    }

    // 3) entangling / extra gate
    const int g2 = (dg2L >> (4 * SL)) & 15;
    switch (g2) {
        case 1: {
            const float r = 0.70710678118654752f;
            realGate<N>(v, laneq, r, r, r, -r);
        } break;
        case 2: applyX<N>(v, laneq); break;
        case 3: applyY<N>(v, laneq); break;
        case 4: applyZ<N>(v, laneq); break;
        case 5: applyCPerm<(1 << N), (1 << N1)>(v, laneq); break;
        case 6: applyCSWAP<N, N1, N2>(v, laneq); break;
        case 7: applyCPerm<(1 << N) | (1 << N1), (1 << N2)>(v, laneq); break;
        case 8: applyCZ<N, N1>(v, laneq); break;
        default: break;
    }
}

// 8 blocks/CU (2nd arg = min waves/EU; for 256-thread blocks it equals blocks/CU).
// VGPR cap at 8 waves/SIMD is 64; kernel uses ~36 — fits without spills.
// Grid = 2048 blocks = 256 CU x 8: the whole launch is one co-resident cohort.
__global__ __launch_bounds__(256, 8) void qsim_kernel(
    const float* __restrict__ feats,    // [B, 8]
    const float* __restrict__ qp,       // [48]
    const int* __restrict__ dry,        // [24]
    const int* __restrict__ drot,       // [24]
    const int* __restrict__ dg2,        // [24]
    float* __restrict__ out,            // [B, 8]
    int B)
{
    __shared__ float2 lds_ry[8][8];     // per-group (c,s) of RY angles, 512 B
    __shared__ float2 lds_rot[48];      // block-uniform (c,s) of trainable angles, 384 B

    const int tid   = threadIdx.x;
    const int laneq = tid & 31;                               // lane within element group
    const int grp   = tid >> 5;                               // group within block (0..7)
    const int b     = blockIdx.x * 8 + grp;                   // batch element

    // ---- prologue: sincos caches (each value computed exactly once per block) ----
    if (tid < 48) {
        const float th = qp[tid] * HALF_INV2PI;               // revolutions of theta/2
        lds_rot[tid] = make_float2(__builtin_amdgcn_cosf(th), __builtin_amdgcn_sinf(th));
    }
    if (laneq < 8) {
        const float th = feats[(size_t)b * NQ + laneq] * HALF_INV2PI;
        lds_ry[grp][laneq] = make_float2(__builtin_amdgcn_cosf(th), __builtin_amdgcn_sinf(th));
    }

    // ---- pack the (uniform) design into SGPRs via readfirstlane (dwordx4 loads) ----
    uint32_t dryP = 0;
    uint64_t drotP = 0;
    uint32_t g2P0 = 0, g2P1 = 0, g2P2 = 0;
#pragma unroll
    for (int q = 0; q < 6; q++) {
        const int4 a = ((const int4*)dry)[q];
        dryP |= (uint32_t)(__builtin_amdgcn_readfirstlane(a.x) & 1) << (4 * q + 0);
        dryP |= (uint32_t)(__builtin_amdgcn_readfirstlane(a.y) & 1) << (4 * q + 1);
        dryP |= (uint32_t)(__builtin_amdgcn_readfirstlane(a.z) & 1) << (4 * q + 2);
        dryP |= (uint32_t)(__builtin_amdgcn_readfirstlane(a.w) & 1) << (4 * q + 3);
        const int4 r = ((const int4*)drot)[q];
        drotP |= (uint64_t)(__builtin_amdgcn_readfirstlane(r.x) & 3) << (8 * q + 0);
        drotP |= (uint64_t)(__builtin_amdgcn_readfirstlane(r.y) & 3) << (8 * q + 2);
        drotP |= (uint64_t)(__builtin_amdgcn_readfirstlane(r.z) & 3) << (8 * q + 4);
        drotP |= (uint64_t)(__builtin_amdgcn_readfirstlane(r.w) & 3) << (8 * q + 6);
        const int4 g = ((const int4*)dg2)[q];
        const uint32_t gg = ((uint32_t)(__builtin_amdgcn_readfirstlane(g.x) & 15))
                          | ((uint32_t)(__builtin_amdgcn_readfirstlane(g.y) & 15) << 4)
                          | ((uint32_t)(__builtin_amdgcn_readfirstlane(g.z) & 15) << 8)
                          | ((uint32_t)(__builtin_amdgcn_readfirstlane(g.w) & 15) << 12);
        if      (q == 0) g2P0 |= gg;
        else if (q == 1) g2P0 |= gg << 16;
        else if (q == 2) g2P1 |= gg;
        else if (q == 3) g2P1 |= gg << 16;
        else if (q == 4) g2P2 |= gg;
        else             g2P2 |= gg << 16;
    }

    __syncthreads();                    // lds_rot written by wave 0, read by all waves

    const float2* ryCS  = &lds_ry[grp][0];
    const float2* rotCS = &lds_rot[0];

    // H^8 |0> = uniform amplitude 1/16
    f32x2 v[8];
#pragma unroll
    for (int i = 0; i < 8; i++) { v[i] = pk2(0.0625f, 0.0f); }

#pragma unroll 1
    for (int layer = 0; layer < 6; layer++) {
        // per-layer design slice (scalar shifts, no memory)
        const int dryL  = (int)((dryP >> (layer * 4)) & 0xF);
        const int drotL = (int)((drotP >> (layer * 8)) & 0xFF);
        const uint32_t g2w = (layer >= 4) ? g2P2 : ((layer >= 2) ? g2P1 : g2P0);
        const int dg2L  = (int)((g2w >> ((layer & 1) * 16)) & 0xFFFF);

        nodeStep<0>(v, laneq, ryCS, rotCS, layer, dryL, drotL, dg2L);
        nodeStep<1>(v, laneq, ryCS, rotCS, layer, dryL, drotL, dg2L);
        nodeStep<2>(v, laneq, ryCS, rotCS, layer, dryL, drotL, dg2L);
        nodeStep<3>(v, laneq, ryCS, rotCS, layer, dryL, drotL, dg2L);
        nodeStep<4>(v, laneq, ryCS, rotCS, layer, dryL, drotL, dg2L);
        nodeStep<5>(v, laneq, ryCS, rotCS, layer, dryL, drotL, dg2L);
        nodeStep<6>(v, laneq, ryCS, rotCS, layer, dryL, drotL, dg2L);
        nodeStep<7>(v, laneq, ryCS, rotCS, layer, dryL, drotL, dg2L);
    }

    // ---- epilogue: <Z_q> ----
    float tot = 0.f, s0 = 0.f, s1 = 0.f, s2 = 0.f;
#pragma unroll
    for (int i = 0; i < 8; i++) {
        const float p = v[i].x * v[i].x + v[i].y * v[i].y;
        tot += p;
        if (!(i & 1)) s0 += p;
        if (!(i & 2)) s1 += p;
        if (!(i & 4)) s2 += p;
    }
    float e[3] = { 2.f * s0 - tot, 2.f * s1 - tot, 2.f * s2 - tot };

    // sum e[0..2] over the 32-lane group
#pragma unroll
    for (int q = 0; q < 3; q++) {
        e[q] += sx<1>(e[q]);
        e[q] += sx<2>(e[q]);
        e[q] += sx<4>(e[q]);
        e[q] += sx<8>(e[q]);
        e[q] += sx<16>(e[q]);
    }
    // FWHT on tot: after 5 stages, laneq = (1<<k) holds <Z_{3+k}>
    { float pv = sx<1>(tot);  tot = (laneq & 1)  ? (pv - tot) : (pv + tot); }
    { float pv = sx<2>(tot);  tot = (laneq & 2)  ? (pv - tot) : (pv + tot); }
    { float pv = sx<4>(tot);  tot = (laneq & 4)  ? (pv - tot) : (pv + tot); }
    { float pv = sx<8>(tot);  tot = (laneq & 8)  ? (pv - tot) : (pv + tot); }
    { float pv = sx<16>(tot); tot = (laneq & 16) ? (pv - tot) : (pv + tot); }

    float* ob = out + (size_t)b * NQ;
    if (laneq == 0) { ob[0] = e[0]; ob[1] = e[1]; ob[2] = e[2]; }
    if (laneq && !(laneq & (laneq - 1)))          // laneq in {1,2,4,8,16}
        ob[3 + __builtin_ctz(laneq)] = tot;
}

extern "C" void kernel_launch(void* const* d_in, const int* in_sizes, int n_in,
                              void* d_out, int out_size, void* d_ws, size_t ws_size,
                              hipStream_t stream)
{
    (void)n_in; (void)out_size; (void)d_ws; (void)ws_size;
    const float* feats   = (const float*)d_in[0];
    const float* qparams = (const float*)d_in[1];
    const int* dry       = (const int*)d_in[2];
    const int* drot      = (const int*)d_in[3];
    const int* dg2       = (const int*)d_in[4];
    float* out           = (float*)d_out;

    const int B = in_sizes[0] / NQ;             // 16384
    const int blocks = (B + 7) / 8;             // 8 elements per 256-thread block
    qsim_kernel<<<blocks, 256, 0, stream>>>(feats, qparams, dry, drot, dg2, out, B);
}

// Round 6
// 106.979 us; speedup vs baseline: 1.0324x; 1.0324x over previous
//
#include <hip/hip_runtime.h>
#include <stdint.h>

#define NQ 8

// v_sin/v_cos take input in REVOLUTIONS. Fold the /2 (half-angle) and 1/2pi
// into one multiplier applied to the raw angle.
#define HALF_INV2PI 0.07957747154594767f   // 0.5 * 1/(2*pi)

// ---- packed 2xf32 (full-rate on CDNA2+): amplitude = (re, im) in a VGPR pair ----
typedef float f32x2 __attribute__((ext_vector_type(2)));

__device__ __forceinline__ f32x2 pk2(float x, float y) { f32x2 r; r.x = x; r.y = y; return r; }
__device__ __forceinline__ f32x2 pkb(float x)          { f32x2 r; r.x = x; r.y = x; return r; }

// d = a*b + c on both halves, one VALU instruction each (VOP3P).
__device__ __forceinline__ f32x2 pk_fma(f32x2 a, f32x2 b, f32x2 c) {
    f32x2 d;
    asm("v_pk_fma_f32 %0, %1, %2, %3" : "=v"(d) : "v"(a), "v"(b), "v"(c));
    return d;
}
__device__ __forceinline__ f32x2 pk_mul(f32x2 a, f32x2 b) {
    f32x2 d;
    asm("v_pk_mul_f32 %0, %1, %2" : "=v"(d) : "v"(a), "v"(b));
    return d;
}
// Cross-component variants via VOP3P op_sel/neg modifiers (packed-f32 op_sel
// selects which 32-bit register of the 64-bit source feeds each result half):
// d.lo = a.hi*b.lo + c.lo ; d.hi = a.lo*(-b.hi) + c.hi    [swap a; negate b's hi term]
__device__ __forceinline__ f32x2 pk_fma_sa_nh(f32x2 a, f32x2 b, f32x2 c) {
    f32x2 d;
    asm("v_pk_fma_f32 %0, %1, %2, %3 op_sel:[1,0,0] op_sel_hi:[0,1,1] neg_hi:[0,1,0]"
        : "=v"(d) : "v"(a), "v"(b), "v"(c));
    return d;
}
// d.lo = a.hi*(-b.lo) + c.lo ; d.hi = a.lo*b.hi + c.hi    [swap a; negate b's lo term]
__device__ __forceinline__ f32x2 pk_fma_sa_nl(f32x2 a, f32x2 b, f32x2 c) {
    f32x2 d;
    asm("v_pk_fma_f32 %0, %1, %2, %3 op_sel:[1,0,0] op_sel_hi:[0,1,1] neg_lo:[0,1,0]"
        : "=v"(d) : "v"(a), "v"(b), "v"(c));
    return d;
}
// d.lo = a.lo*b.lo + c.lo ; d.hi = a.hi*(-b.hi) + c.hi    [no swap; negate b's hi term]
__device__ __forceinline__ f32x2 pk_fma_nh(f32x2 a, f32x2 b, f32x2 c) {
    f32x2 d;
    asm("v_pk_fma_f32 %0, %1, %2, %3 neg_hi:[0,1,0]"
        : "=v"(d) : "v"(a), "v"(b), "v"(c));
    return d;
}

// ---- cross-lane xor exchange within aligned 32-lane groups ----
// xor1/xor2: DPP quad_perm; xor8: DPP row_ror:8 (within 16-lane rows, ror8 == xor8).
// xor4/xor16: ds_swizzle BitMode (operates within 32-lane groups).
template<int XM>
__device__ __forceinline__ float sx(float v) {
    if constexpr (XM == 0) return v;
    const int x = __float_as_int(v);
    int r;
    if constexpr (XM == 1)      r = __builtin_amdgcn_update_dpp(0, x, 0xB1,  0xF, 0xF, true); // quad [1,0,3,2]
    else if constexpr (XM == 2) r = __builtin_amdgcn_update_dpp(0, x, 0x4E,  0xF, 0xF, true); // quad [2,3,0,1]
    else if constexpr (XM == 8) r = __builtin_amdgcn_update_dpp(0, x, 0x128, 0xF, 0xF, true); // row_ror:8
    else                        r = __builtin_amdgcn_ds_swizzle(x, (XM << 10) | 0x1F);        // 4, 16
    return __int_as_float(r);
}

// full (re,im) partner fetch: two 32-bit exchanges
template<int XM>
__device__ __forceinline__ f32x2 sxp(f32x2 v) {
    f32x2 r; r.x = sx<XM>(v.x); r.y = sx<XM>(v.y); return r;
}
// partner fetched with components SWAPPED: returns (partner.im, partner.re)
template<int XM>
__device__ __forceinline__ f32x2 sxp_swap(f32x2 v) {
    f32x2 r; r.x = sx<XM>(v.y); r.y = sx<XM>(v.x); return r;
}

__device__ __forceinline__ void swapv(f32x2& a, f32x2& b) { f32x2 t = a; a = b; b = t; }

// Layout: amp index g = i | (laneq<<3); qubit k -> bit k of g.
// Qubits 0..2 = local bits (i in [0,8)), qubits 3..7 = lane bits (laneq in [0,32)).

// ---- real 2x2 [[a,b],[d,e]] on qubit Q — packed: same real coef on re and im ----
template<int Q>
__device__ __forceinline__ void realGate(f32x2 (&v)[8], int laneq,
                                         float a, float b, float d, float e)
{
    if constexpr (Q < 3) {
        constexpr int M = 1 << Q;
        const f32x2 a2 = pkb(a), b2 = pkb(b), d2 = pkb(d), e2 = pkb(e);
#pragma unroll
        for (int i = 0; i < 8; i++) if (!(i & M)) {
            const int j = i | M;
            const f32x2 x0 = v[i], x1 = v[j];
            v[i] = pk_fma(a2, x0, pk_mul(b2, x1));
            v[j] = pk_fma(d2, x0, pk_mul(e2, x1));
        }
    } else {
        constexpr int XM = 1 << (Q - 3);
        const int bit = (laneq >> (Q - 3)) & 1;
        const f32x2 sc2 = pkb(bit ? e : a);   // self coefficient
        const f32x2 pc2 = pkb(bit ? d : b);   // partner coefficient
#pragma unroll
        for (int i = 0; i < 8; i++) {
            const f32x2 p = sxp<XM>(v[i]);
            v[i] = pk_fma(sc2, v[i], pk_mul(pc2, p));
        }
    }
}

// ---- RX: [[c, -i s], [-i s, c]] ----
// new.re = c*re + s*partner.im ; new.im = c*im - s*partner.re
template<int Q>
__device__ __forceinline__ void applyRX(f32x2 (&v)[8], int laneq, float c, float s)
{
    const f32x2 cc = pkb(c), ss = pkb(s);
    if constexpr (Q < 3) {
        constexpr int M = 1 << Q;
#pragma unroll
        for (int i = 0; i < 8; i++) if (!(i & M)) {
            const int j = i | M;
            const f32x2 x0 = v[i], x1 = v[j];
            // (c*x0r + s*x1i, c*x0i - s*x1r) via op_sel swap of the partner
            v[i] = pk_fma_sa_nh(x1, ss, pk_mul(cc, x0));
            v[j] = pk_fma_sa_nh(x0, ss, pk_mul(cc, x1));
        }
    } else {
        constexpr int XM = 1 << (Q - 3);
#pragma unroll
        for (int i = 0; i < 8; i++) {
            const f32x2 ps = sxp_swap<XM>(v[i]);   // (partner.im, partner.re)
            v[i] = pk_fma_nh(ps, ss, pk_mul(cc, v[i]));
        }
    }
}

// ---- RZ: diag(c - i s, c + i s) — shuffle-free, 2 pk ops per amp ----
template<int Q>
__device__ __forceinline__ void applyRZ(f32x2 (&v)[8], int laneq, float c, float s)
{
    const f32x2 cc = pkb(c);
    if constexpr (Q >= 3) {
        const int bit = (laneq >> (Q - 3)) & 1;
        const float t = bit ? -s : s;
        const f32x2 tt = pkb(t);
#pragma unroll
        for (int i = 0; i < 8; i++)
            v[i] = pk_fma_sa_nh(v[i], tt, pk_mul(cc, v[i]));   // (c*r + t*i, c*i - t*r)
    } else {
        const f32x2 ss = pkb(s);
#pragma unroll
        for (int i = 0; i < 8; i++) {
            if ((i >> Q) & 1) v[i] = pk_fma_sa_nl(v[i], ss, pk_mul(cc, v[i])); // t = -s
            else              v[i] = pk_fma_sa_nh(v[i], ss, pk_mul(cc, v[i])); // t = +s
        }
    }
}

// ---- Pauli Z ----
template<int Q>
__device__ __forceinline__ void applyZ(f32x2 (&v)[8], int laneq)
{
    if constexpr (Q >= 3) {
        const bool f = ((laneq >> (Q - 3)) & 1) != 0;
#pragma unroll
        for (int i = 0; i < 8; i++) {
            v[i].x = f ? -v[i].x : v[i].x;
            v[i].y = f ? -v[i].y : v[i].y;
        }
    } else {
#pragma unroll
        for (int i = 0; i < 8; i++) if ((i >> Q) & 1) {
            v[i].x = -v[i].x; v[i].y = -v[i].y;
        }
    }
}

// ---- Pauli X ----
template<int Q>
__device__ __forceinline__ void applyX(f32x2 (&v)[8], int laneq)
{
    if constexpr (Q < 3) {
        constexpr int M = 1 << Q;
#pragma unroll
        for (int i = 0; i < 8; i++) if (!(i & M)) {
            swapv(v[i], v[i | M]);
        }
    } else {
        constexpr int XM = 1 << (Q - 3);
#pragma unroll
        for (int i = 0; i < 8; i++) {
            v[i] = sxp<XM>(v[i]);
        }
    }
}

// ---- Pauli Y: [[0,-i],[i,0]] ----
template<int Q>
__device__ __forceinline__ void applyY(f32x2 (&v)[8], int laneq)
{
    if constexpr (Q < 3) {
        constexpr int M = 1 << Q;
#pragma unroll
        for (int i = 0; i < 8; i++) if (!(i & M)) {
            const int j = i | M;
            const f32x2 x0 = v[i], x1 = v[j];
            v[i] = pk2(x1.y, -x1.x);
            v[j] = pk2(-x0.y, x0.x);
        }
    } else {
        constexpr int XM = 1 << (Q - 3);
        const int bit = (laneq >> (Q - 3)) & 1;
#pragma unroll
        for (int i = 0; i < 8; i++) {
            const f32x2 p = sxp<XM>(v[i]);
            v[i].x = bit ? -p.y : p.y;
            v[i].y = bit ? p.x : -p.x;
        }
    }
}

// ---- CZ(C,T): sign flip when both bits set — shuffle-free ----
template<int C, int T>
__device__ __forceinline__ void applyCZ(f32x2 (&v)[8], int laneq)
{
#pragma unroll
    for (int i = 0; i < 8; i++) {
        const int g = i | (laneq << 3);
        const bool f = (((g >> C) & (g >> T)) & 1) != 0;
        v[i].x = f ? -v[i].x : v[i].x;
        v[i].y = f ? -v[i].y : v[i].y;
    }
}

// ---- controlled bit-flip: new[g] = old[g ^ M] when (g & CM) == CM ----
template<int CM, int M>
__device__ __forceinline__ void applyCPerm(f32x2 (&v)[8], int laneq)
{
    constexpr int LX  = M >> 3;    // target in lane bits -> exchange mask
    constexpr int PL  = M & 7;     // target in local bits
    constexpr int CML = CM & 7;    // controls in local bits
    constexpr int CMH = CM >> 3;   // controls in lane bits
    if constexpr (LX != 0) {
#pragma unroll
        for (int i = 0; i < 8; i++) {
            if ((i & CML) == CML) {
                const f32x2 p = sxp<LX>(v[i]);
                if constexpr (CMH != 0) {
                    const bool c = (laneq & CMH) == CMH;
                    v[i].x = c ? p.x : v[i].x;
                    v[i].y = c ? p.y : v[i].y;
                } else {
                    v[i] = p;
                }
            }
        }
    } else {
#pragma unroll
        for (int i = 0; i < 8; i++) {
            if (!(i & PL) && ((i & CML) == CML)) {
                const int j = i | PL;
                if constexpr (CMH != 0) {
                    const bool c = (laneq & CMH) == CMH;
                    const f32x2 t0 = v[i];
                    v[i].x = c ? v[j].x : v[i].x;  v[i].y = c ? v[j].y : v[i].y;
                    v[j].x = c ? t0.x : v[j].x;    v[j].y = c ? t0.y : v[j].y;
                } else {
                    swapv(v[i], v[j]);
                }
            }
        }
    }
}

// ---- CSWAP(C; T1,T2): swap bits T1,T2 when control set ----
template<int C, int T1, int T2>
__device__ __forceinline__ void applyCSWAP(f32x2 (&v)[8], int laneq)
{
    constexpr int M  = (1 << T1) | (1 << T2);
    constexpr int LX = M >> 3;
    constexpr int PL = M & 7;

    if constexpr (LX == 0) {
        // both targets local: representative i has T1-bit=1, T2-bit=0
#pragma unroll
        for (int i = 0; i < 8; i++) {
            if (((i >> T1) & 1) && !((i >> T2) & 1)) {
                bool skip = false;
                if constexpr (C < 3) { if (!((i >> C) & 1)) skip = true; }
                if (!skip) {
                    const int j = i ^ PL;
                    if constexpr (C >= 3) {
                        const bool c = ((laneq >> (C - 3)) & 1) != 0;
                        const f32x2 t0 = v[i];
                        v[i].x = c ? v[j].x : v[i].x;  v[i].y = c ? v[j].y : v[i].y;
                        v[j].x = c ? t0.x : v[j].x;    v[j].y = c ? t0.y : v[j].y;
                    } else {
                        swapv(v[i], v[j]);
                    }
                }
            }
        }
    } else if constexpr (PL == 0) {
        // both targets in lane bits
        bool c = ((((laneq >> (T1 - 3)) ^ (laneq >> (T2 - 3))) & 1) != 0);
        if constexpr (C >= 3) c = c && (((laneq >> (C - 3)) & 1) != 0);
#pragma unroll
        for (int i = 0; i < 8; i++) {
            bool skip = false;
            if constexpr (C < 3) { if (!((i >> C) & 1)) skip = true; }
            if (!skip) {
                const f32x2 p = sxp<LX>(v[i]);
                v[i].x = c ? p.x : v[i].x;
                v[i].y = c ? p.y : v[i].y;
            }
        }
    } else {
        // mixed: one local target (PL), one lane target (LX)
        constexpr int TL = (PL == (1 << T1)) ? T2 : T1;    // lane-resident target
        const bool laneT = ((laneq >> (TL - 3)) & 1) != 0;
        bool cc = true;
        if constexpr (C >= 3) cc = ((laneq >> (C - 3)) & 1) != 0;
#pragma unroll
        for (int i = 0; i < 8; i++) {
            if (!(i & PL)) {
                bool skip = false;
                if constexpr (C < 3) { if (!((i >> C) & 1)) skip = true; }
                if (!skip) {
                    const int j = i | PL;
                    // read partner-lane values before any write (lockstep)
                    const f32x2 a = sxp<LX>(v[j]);  // -> v[i]
                    const f32x2 b = sxp<LX>(v[i]);  // -> v[j]
                    const bool ci = cc && laneT;
                    const bool cj = cc && !laneT;
                    v[i].x = ci ? a.x : v[i].x;  v[i].y = ci ? a.y : v[i].y;
                    v[j].x = cj ? b.x : v[j].x;  v[j].y = cj ? b.y : v[j].y;
                }
            }
        }
    }
}

// ---- one node step; node N compile-time; design bits passed as packed scalars ----
// dryL: 4 bits (node&3), drotL: 8 bits (2 per node&3), dg2L: 16 bits (4 per node&3)
// All sincos values come from LDS (computed once in the prologue):
//   ryCS[n]  = (cos(feat_n/2), sin(feat_n/2))   per batch element (broadcast in group)
//   rotCS[k] = (cos(qp_k/2),  sin(qp_k/2))      block-uniform broadcast
template<int N>
__device__ __forceinline__ void nodeStep(f32x2 (&v)[8], int laneq,
                                         const float2* ryCS, const float2* rotCS,
                                         int layer, int dryL, int drotL, int dg2L)
{
    constexpr int N1 = (N + 1) & 7;
    constexpr int N2 = (N + 2) & 7;
    constexpr int SL = N & 3;

    const bool ryOn = ((dryL >> SL) & 1) != 0;
    const int rot = (drotL >> (2 * SL)) & 3;

    if (rot < 3) {
        const float2 t = rotCS[layer * NQ + N];     // ds_read_b64, uniform addr
        const float cb = t.x, sb = t.y;
        if (ryOn && rot == 1) {
            // RY(a) then RY(b) == RY(a+b): angle-sum on the cached pairs
            const float2 a = ryCS[N];
            const float c = cb * a.x - sb * a.y;
            const float s = sb * a.x + cb * a.y;
            realGate<N>(v, laneq, c, -s, s, c);
        } else {
            if (ryOn) {
                const float2 a = ryCS[N];
                realGate<N>(v, laneq, a.x, -a.y, a.y, a.x);
            }
            if (rot == 0)      applyRX<N>(v, laneq, cb, sb);
            else if (rot == 1) realGate<N>(v, laneq, cb, -sb, sb, cb);
            else               applyRZ<N>(v, laneq, cb, sb);
        }
    } else if (ryOn) {
        const float2 a = ryCS[N];
        realGate<N>(v, laneq, a.x, -a.y, a.y, a.x);
    }

    // 3) entangling / extra gate
    const int g2 = (dg2L >> (4 * SL)) & 15;
    switch (g2) {
        case 1: {
            const float r = 0.70710678118654752f;
            realGate<N>(v, laneq, r, r, r, -r);
        } break;
        case 2: applyX<N>(v, laneq); break;
        case 3: applyY<N>(v, laneq); break;
        case 4: applyZ<N>(v, laneq); break;
        case 5: applyCPerm<(1 << N), (1 << N1)>(v, laneq); break;
        case 6: applyCSWAP<N, N1, N2>(v, laneq); break;
        case 7: applyCPerm<(1 << N) | (1 << N1), (1 << N2)>(v, laneq); break;
        case 8: applyCZ<N, N1>(v, laneq); break;
        default: break;
    }
}

// 6 blocks/CU (2nd arg = min waves/EU; for 256-thread blocks it equals blocks/CU).
// VGPR cap at 6 waves/SIMD is ~85 — kernel's natural ~36-40 fits WITHOUT the
// allocator squeeze that caused spills at the 8-block tier (round 5: 24 MB of
// scratch traffic, occupancy stuck at 53%). 4-block tier measured 59.4 us.
__global__ __launch_bounds__(256, 6) void qsim_kernel(
    const float* __restrict__ feats,    // [B, 8]
    const float* __restrict__ qp,       // [48]
    const int* __restrict__ dry,        // [24]
    const int* __restrict__ drot,       // [24]
    const int* __restrict__ dg2,        // [24]
    float* __restrict__ out,            // [B, 8]
    int B)
{
    __shared__ float2 lds_ry[8][8];     // per-group (c,s) of RY angles, 512 B
    __shared__ float2 lds_rot[48];      // block-uniform (c,s) of trainable angles, 384 B

    const int tid   = threadIdx.x;
    const int laneq = tid & 31;                               // lane within element group
    const int grp   = tid >> 5;                               // group within block (0..7)
    const int b     = blockIdx.x * 8 + grp;                   // batch element

    // ---- prologue: sincos caches (each value computed exactly once per block) ----
    if (tid < 48) {
        const float th = qp[tid] * HALF_INV2PI;               // revolutions of theta/2
        lds_rot[tid] = make_float2(__builtin_amdgcn_cosf(th), __builtin_amdgcn_sinf(th));
    }
    if (laneq < 8) {
        const float th = feats[(size_t)b * NQ + laneq] * HALF_INV2PI;
        lds_ry[grp][laneq] = make_float2(__builtin_amdgcn_cosf(th), __builtin_amdgcn_sinf(th));
    }

    // ---- pack the (uniform) design into SGPRs via readfirstlane (dwordx4 loads) ----
    uint32_t dryP = 0;
    uint64_t drotP = 0;
    uint32_t g2P0 = 0, g2P1 = 0, g2P2 = 0;
#pragma unroll
    for (int q = 0; q < 6; q++) {
        const int4 a = ((const int4*)dry)[q];
        dryP |= (uint32_t)(__builtin_amdgcn_readfirstlane(a.x) & 1) << (4 * q + 0);
        dryP |= (uint32_t)(__builtin_amdgcn_readfirstlane(a.y) & 1) << (4 * q + 1);
        dryP |= (uint32_t)(__builtin_amdgcn_readfirstlane(a.z) & 1) << (4 * q + 2);
        dryP |= (uint32_t)(__builtin_amdgcn_readfirstlane(a.w) & 1) << (4 * q + 3);
        const int4 r = ((const int4*)drot)[q];
        drotP |= (uint64_t)(__builtin_amdgcn_readfirstlane(r.x) & 3) << (8 * q + 0);
        drotP |= (uint64_t)(__builtin_amdgcn_readfirstlane(r.y) & 3) << (8 * q + 2);
        drotP |= (uint64_t)(__builtin_amdgcn_readfirstlane(r.z) & 3) << (8 * q + 4);
        drotP |= (uint64_t)(__builtin_amdgcn_readfirstlane(r.w) & 3) << (8 * q + 6);
        const int4 g = ((const int4*)dg2)[q];
        const uint32_t gg = ((uint32_t)(__builtin_amdgcn_readfirstlane(g.x) & 15))
                          | ((uint32_t)(__builtin_amdgcn_readfirstlane(g.y) & 15) << 4)
                          | ((uint32_t)(__builtin_amdgcn_readfirstlane(g.z) & 15) << 8)
                          | ((uint32_t)(__builtin_amdgcn_readfirstlane(g.w) & 15) << 12);
        if      (q == 0) g2P0 |= gg;
        else if (q == 1) g2P0 |= gg << 16;
        else if (q == 2) g2P1 |= gg;
        else if (q == 3) g2P1 |= gg << 16;
        else if (q == 4) g2P2 |= gg;
        else             g2P2 |= gg << 16;
    }

    __syncthreads();                    // lds_rot written by wave 0, read by all waves

    const float2* ryCS  = &lds_ry[grp][0];
    const float2* rotCS = &lds_rot[0];

    // H^8 |0> = uniform amplitude 1/16
    f32x2 v[8];
#pragma unroll
    for (int i = 0; i < 8; i++) { v[i] = pk2(0.0625f, 0.0f); }

#pragma unroll 1
    for (int layer = 0; layer < 6; layer++) {
        // per-layer design slice (scalar shifts, no memory)
        const int dryL  = (int)((dryP >> (layer * 4)) & 0xF);
        const int drotL = (int)((drotP >> (layer * 8)) & 0xFF);
        const uint32_t g2w = (layer >= 4) ? g2P2 : ((layer >= 2) ? g2P1 : g2P0);
        const int dg2L  = (int)((g2w >> ((layer & 1) * 16)) & 0xFFFF);

        nodeStep<0>(v, laneq, ryCS, rotCS, layer, dryL, drotL, dg2L);
        nodeStep<1>(v, laneq, ryCS, rotCS, layer, dryL, drotL, dg2L);
        nodeStep<2>(v, laneq, ryCS, rotCS, layer, dryL, drotL, dg2L);
        nodeStep<3>(v, laneq, ryCS, rotCS, layer, dryL, drotL, dg2L);
        nodeStep<4>(v, laneq, ryCS, rotCS, layer, dryL, drotL, dg2L);
        nodeStep<5>(v, laneq, ryCS, rotCS, layer, dryL, drotL, dg2L);
        nodeStep<6>(v, laneq, ryCS, rotCS, layer, dryL, drotL, dg2L);
        nodeStep<7>(v, laneq, ryCS, rotCS, layer, dryL, drotL, dg2L);
    }

    // ---- epilogue: <Z_q> ----
    float tot = 0.f, s0 = 0.f, s1 = 0.f, s2 = 0.f;
#pragma unroll
    for (int i = 0; i < 8; i++) {
        const float p = v[i].x * v[i].x + v[i].y * v[i].y;
        tot += p;
        if (!(i & 1)) s0 += p;
        if (!(i & 2)) s1 += p;
        if (!(i & 4)) s2 += p;
    }
    float e[3] = { 2.f * s0 - tot, 2.f * s1 - tot, 2.f * s2 - tot };

    // sum e[0..2] over the 32-lane group
#pragma unroll
    for (int q = 0; q < 3; q++) {
        e[q] += sx<1>(e[q]);
        e[q] += sx<2>(e[q]);
        e[q] += sx<4>(e[q]);
        e[q] += sx<8>(e[q]);
        e[q] += sx<16>(e[q]);
    }
    // FWHT on tot: after 5 stages, laneq = (1<<k) holds <Z_{3+k}>
    { float pv = sx<1>(tot);  tot = (laneq & 1)  ? (pv - tot) : (pv + tot); }
    { float pv = sx<2>(tot);  tot = (laneq & 2)  ? (pv - tot) : (pv + tot); }
    { float pv = sx<4>(tot);  tot = (laneq & 4)  ? (pv - tot) : (pv + tot); }
    { float pv = sx<8>(tot);  tot = (laneq & 8)  ? (pv - tot) : (pv + tot); }
    { float pv = sx<16>(tot); tot = (laneq & 16) ? (pv - tot) : (pv + tot); }

    float* ob = out + (size_t)b * NQ;
    if (laneq == 0) { ob[0] = e[0]; ob[1] = e[1]; ob[2] = e[2]; }
    if (laneq && !(laneq & (laneq - 1)))          // laneq in {1,2,4,8,16}
        ob[3 + __builtin_ctz(laneq)] = tot;
}

extern "C" void kernel_launch(void* const* d_in, const int* in_sizes, int n_in,
                              void* d_out, int out_size, void* d_ws, size_t ws_size,
                              hipStream_t stream)
{
    (void)n_in; (void)out_size; (void)d_ws; (void)ws_size;
    const float* feats   = (const float*)d_in[0];
    const float* qparams = (const float*)d_in[1];
    const int* dry       = (const int*)d_in[2];
    const int* drot      = (const int*)d_in[3];
    const int* dg2       = (const int*)d_in[4];
    float* out           = (float*)d_out;

    const int B = in_sizes[0] / NQ;             // 16384
    const int blocks = (B + 7) / 8;             // 8 elements per 256-thread block
    qsim_kernel<<<blocks, 256, 0, stream>>>(feats, qparams, dry, drot, dg2, out, B);
}